// Round 3
// baseline (534.267 us; speedup 1.0000x reference)
//
#include <hip/hip_runtime.h>

// ChemResBlock: S=16, A=512, F=64, L=12, 3 layers x 2 convs (shared weights/layer).
// Re-associated: yT[s][o][k*12+l] = sum_f x[s,k,f] w[o,l,f]   (stage A, tiny)
//                out[s,a,o] = sum_{kl} connB[s,a,kl] * yT[s][o][kl] + bondW (+node), relu
// connB = conn cast to bf16 elementwise (natural layout IS the GEMM A layout).

typedef __attribute__((ext_vector_type(8))) short bf16x8;
typedef __attribute__((ext_vector_type(4))) float f32x4;
typedef unsigned short u16;
typedef unsigned int u32;

__device__ __forceinline__ u16 f2bf(float f) {
  union { float f; u32 u; } x; x.f = f;
  u32 r = x.u + 0x7fffu + ((x.u >> 16) & 1u);   // RNE
  return (u16)(r >> 16);
}

__device__ __forceinline__ void gload16(const void* g, void* l) {
  __builtin_amdgcn_global_load_lds((const __attribute__((address_space(1))) u32*)g,
                                   (__attribute__((address_space(3))) u32*)l, 16, 0, 0);
}

// ---------- prep ----------

// f32 -> bf16 elementwise, 8 elems/thread/iter (2x float4 in, 2x ushort4 out)
__global__ __launch_bounds__(256) void k_cast_bf16(const float* __restrict__ src,
                                                   u16* __restrict__ dst, unsigned n8) {
  const unsigned stride = gridDim.x * 256;
  for (unsigned j = blockIdx.x * 256 + threadIdx.x; j < n8; j += stride) {
    const float4* s4 = (const float4*)src;
    float4 a = s4[2 * (size_t)j], b = s4[2 * (size_t)j + 1];
    ushort4 lo, hi;
    lo.x = f2bf(a.x); lo.y = f2bf(a.y); lo.z = f2bf(a.z); lo.w = f2bf(a.w);
    hi.x = f2bf(b.x); hi.y = f2bf(b.y); hi.z = f2bf(b.z); hi.w = f2bf(b.w);
    ((ushort4*)dst)[2 * (size_t)j] = lo;
    ((ushort4*)dst)[2 * (size_t)j + 1] = hi;
  }
}

// filters (3,64,12,66) -> wA [i][(l*64+o)][f] bf16 (drop bond cols)
__global__ __launch_bounds__(256) void k_w_pack(const float* __restrict__ filters,
                                                u16* __restrict__ wA) {
  int tid = blockIdx.x * 256 + threadIdx.x;  // < 3*768*64 = 147456
  int i = tid / 49152;
  int rem = tid - i * 49152;
  int row = rem >> 6, f = rem & 63;          // row = l*64+o
  int l = row >> 6, o = row & 63;
  wA[tid] = f2bf(filters[((size_t)((i * 64 + o) * 12 + l)) * 66 + f]);
}

// bondW[i][(s*512+a)*64+o] = sum_{l,j} bond[s,a,l,j] * filters[i,o,l,64+j]
__global__ __launch_bounds__(192) void k_bondw(const float* __restrict__ bond,
                                               const float* __restrict__ filters,
                                               float* __restrict__ bondW) {
  int blk = blockIdx.x;                      // s*512 + a
  int t = threadIdx.x;                       // 192 = 3 filters x 64 o
  __shared__ float lb[24];
  if (t < 24) lb[t] = bond[(size_t)blk * 24 + t];
  __syncthreads();
  int i = t >> 6, o = t & 63;
  float acc = 0.f;
#pragma unroll
  for (int l = 0; l < 12; ++l) {
    const float* wr = filters + ((size_t)((i * 64 + o) * 12 + l)) * 66 + 64;
    acc += lb[l * 2 + 0] * wr[0] + lb[l * 2 + 1] * wr[1];
  }
  bondW[(size_t)i * 524288 + (size_t)blk * 64 + o] = acc;
}

// ---------- stage A: yT[s][o][k*12+l] = sum_f x[s,k,f] wA[(l*64+o)][f] ----------
// block = (ktile of 32, s); MFMA D[o][k] per l; LDS transpose -> 24B rows of yT.
// Z = [l][o][k pad 36] u16 -> 55,296 B static LDS (under 64 KiB limit).
__global__ __launch_bounds__(256) void k_stageA(const u16* __restrict__ x,
                                                const u16* __restrict__ wA,
                                                u16* __restrict__ yT) {
  const int s = blockIdx.y, k0 = blockIdx.x * 32;
  __shared__ u16 Z[12 * 64 * 36];
  const int tid = threadIdx.x, lane = tid & 63, wid = tid >> 6;
  const int r = lane & 15, g = lane >> 4;
  const u16* xb = x + (size_t)s * 32768 + (size_t)k0 * 64;

  bf16x8 bv[2][2];                           // [kt][ks]: x frags, col=k, K=f
#pragma unroll
  for (int kt = 0; kt < 2; ++kt)
#pragma unroll
    for (int ks = 0; ks < 2; ++ks)
      bv[kt][ks] = *(const bf16x8*)&xb[(size_t)(kt * 16 + r) * 64 + ks * 32 + g * 8];

#pragma unroll
  for (int lw = 0; lw < 3; ++lw) {
    const int l = wid * 3 + lw;
    f32x4 acc[4][2] = {};                    // [ot][kt]
#pragma unroll
    for (int ks = 0; ks < 2; ++ks)
#pragma unroll
      for (int ot = 0; ot < 4; ++ot) {
        bf16x8 av = *(const bf16x8*)&wA[(size_t)(l * 64 + ot * 16 + r) * 64 + ks * 32 + g * 8];
#pragma unroll
        for (int kt = 0; kt < 2; ++kt)
          acc[ot][kt] = __builtin_amdgcn_mfma_f32_16x16x32_bf16(av, bv[kt][ks], acc[ot][kt], 0, 0, 0);
      }
#pragma unroll
    for (int ot = 0; ot < 4; ++ot)
#pragma unroll
      for (int kt = 0; kt < 2; ++kt)
#pragma unroll
        for (int r2 = 0; r2 < 4; ++r2) {
          int o = ot * 16 + g * 4 + r2, k = kt * 16 + r;
          Z[l * 2304 + o * 36 + k] = f2bf(acc[ot][kt][r2]);
        }
  }
  __syncthreads();
  u16* yb = yT + (size_t)s * 393216;
#pragma unroll
  for (int it = 0; it < 8; ++it) {
    int idx = it * 256 + tid;                // 64 o x 32 k
    int o = idx >> 5, k = idx & 31;
    u16 v[12];
#pragma unroll
    for (int l = 0; l < 12; ++l) v[l] = Z[l * 2304 + o * 36 + k];
    ushort4* dst = (ushort4*)&yb[(size_t)o * 6144 + (size_t)(k0 + k) * 12];
    ushort4 w0, w1, w2;
    w0.x = v[0]; w0.y = v[1]; w0.z = v[2]; w0.w = v[3];
    w1.x = v[4]; w1.y = v[5]; w1.z = v[6]; w1.w = v[7];
    w2.x = v[8]; w2.y = v[9]; w2.z = v[10]; w2.w = v[11];
    dst[0] = w0; dst[1] = w1; dst[2] = w2;
  }
}

// ---------- stage B: out[s][a][o] = connB[s][a][:] . yT[s][o][:] ----------
// Mtile=64 x Ntile=64, K=6144, 8 waves; XCD swizzle: 2 s per XCD.
__global__ __launch_bounds__(512) void k_stageB(const u16* __restrict__ connB,
                                                const u16* __restrict__ yT,
                                                const float* __restrict__ bW,
                                                const float* __restrict__ node,
                                                float* __restrict__ outF,
                                                u16* __restrict__ xn,
                                                int addNode, int writeF32) {
  const int lb = blockIdx.x;                 // 0..127
  const int xcd = lb & 7, q = lb >> 3;
  const int s = xcd * 2 + (q & 1), bx = q >> 1;
  const int row0 = bx * 64;
  const u16* Ab = connB + (size_t)s * 3145728 + (size_t)row0 * 6144;
  const u16* Bb = yT + (size_t)s * 393216;
  __shared__ __align__(16) u16 lA[2][64 * 32];
  __shared__ __align__(16) u16 lB[2][64 * 32];
  const int tid = threadIdx.x, lane = tid & 63, wid = tid >> 6;
  const int rsub = lane >> 2, slot = lane & 3;
  const int r = lane & 15, g = lane >> 4;
  const int wr = wid & 3, wc = wid >> 2;     // wave row-quarter / col-half

  // staging role: waves 0-3 -> A row-groups, 4-7 -> B row-groups (1 gload each)
  const int isA = wid < 4;
  const int r0i = (isA ? wid : wid - 4) << 4;
  const int srow = r0i + rsub;
  const int ss = slot ^ ((srow >> 1) & 3);
  const u16* sbase = (isA ? Ab : Bb) + (size_t)srow * 6144 + ss * 8;

  f32x4 acc[2] = {};

  gload16(sbase, (isA ? lA[0] : lB[0]) + r0i * 32);
  __syncthreads();
  for (int st = 0; st < 192; ++st) {
    const int cur = st & 1;
    if (st < 191)
      gload16(sbase + (size_t)(st + 1) * 32, (isA ? lA[cur ^ 1] : lB[cur ^ 1]) + r0i * 32);
    bf16x8 av, bv[2];
    {
      int row = wr * 16 + r;
      av = *(const bf16x8*)&lA[cur][row * 32 + ((g ^ ((row >> 1) & 3)) << 3)];
    }
#pragma unroll
    for (int c = 0; c < 2; ++c) {
      int col = wc * 32 + c * 16 + r;
      bv[c] = *(const bf16x8*)&lB[cur][col * 32 + ((g ^ ((col >> 1) & 3)) << 3)];
    }
#pragma unroll
    for (int c = 0; c < 2; ++c)
      acc[c] = __builtin_amdgcn_mfma_f32_16x16x32_bf16(av, bv[c], acc[c], 0, 0, 0);
    __syncthreads();
  }
#pragma unroll
  for (int c = 0; c < 2; ++c)
#pragma unroll
    for (int r2 = 0; r2 < 4; ++r2) {
      int m = row0 + wr * 16 + g * 4 + r2;
      int o = wc * 32 + c * 16 + r;
      size_t gm = (size_t)s * 512 + m;
      float v = acc[c][r2] + bW[gm * 64 + o];
      if (addNode) v += node[gm * 64 + o];
      v = fmaxf(v, 0.f);
      if (writeF32) outF[gm * 64 + o] = v;
      else          xn[gm * 64 + o] = f2bf(v);
    }
}

// ---------- fallback (f32, correct, slow) if ws too small ----------
__global__ __launch_bounds__(256) void k_fb_conv(const float* __restrict__ x,
                                                 const float* __restrict__ conn,
                                                 const float* __restrict__ bond,
                                                 const float* __restrict__ filt,
                                                 const float* __restrict__ node,
                                                 float* __restrict__ out, int addNode) {
  const int s = blockIdx.y, a = blockIdx.x;
  const int t = threadIdx.x;
  const int f = t & 63, lg = t >> 6;
  __shared__ float ncv[12 * 64];
  __shared__ float red[4][64];
  const float* cb = conn + ((size_t)(s * 512 + a)) * 6144;
  const float* xb = x + (size_t)s * 32768;
  float a0 = 0.f, a1 = 0.f, a2 = 0.f;
  for (int k = 0; k < 512; ++k) {
    float xv = xb[k * 64 + f];
    const float* cr = cb + k * 12 + lg * 3;
    a0 += cr[0] * xv; a1 += cr[1] * xv; a2 += cr[2] * xv;
  }
  ncv[(lg * 3 + 0) * 64 + f] = a0;
  ncv[(lg * 3 + 1) * 64 + f] = a1;
  ncv[(lg * 3 + 2) * 64 + f] = a2;
  __syncthreads();
  float p = 0.f;
  for (int l = lg * 3; l < lg * 3 + 3; ++l) {
    const float* wr = filt + ((size_t)(f * 12 + l)) * 66;
    float q = 0.f;
    for (int f2 = 0; f2 < 64; ++f2) q += ncv[l * 64 + f2] * wr[f2];
    q += bond[((size_t)(s * 512 + a) * 12 + l) * 2 + 0] * wr[64];
    q += bond[((size_t)(s * 512 + a) * 12 + l) * 2 + 1] * wr[65];
    p += q;
  }
  red[lg][f] = p;
  __syncthreads();
  if (t < 64) {
    float v = red[0][t] + red[1][t] + red[2][t] + red[3][t];
    if (addNode) v += node[((size_t)(s * 512 + a)) * 64 + t];
    out[((size_t)(s * 512 + a)) * 64 + t] = fmaxf(v, 0.f);
  }
}

extern "C" void kernel_launch(void* const* d_in, const int* in_sizes, int n_in,
                              void* d_out, int out_size, void* d_ws, size_t ws_size,
                              hipStream_t stream) {
  (void)in_sizes; (void)n_in; (void)out_size;
  const float* node    = (const float*)d_in[0];
  const float* conn    = (const float*)d_in[1];
  const float* bond    = (const float*)d_in[2];
  const float* filters = (const float*)d_in[3];
  float* outF = (float*)d_out;

  const size_t OFF_CONNB = 0;           // 16*512*6144*2  = 100,663,296
  const size_t OFF_YT    = 100663296;   // 16*64*6144*2   =  12,582,912
  const size_t OFF_XA    = 113246208;   // 16*512*64*2    =   1,048,576
  const size_t OFF_XB    = 114294784;   //                    1,048,576
  const size_t OFF_WA    = 115343360;   // 3*768*64*2     =     294,912
  const size_t OFF_BW    = 115638272;   // 3*16*512*64*4  =   6,291,456
  const size_t WS_NEED   = 121929728;

  if (ws_size >= WS_NEED) {
    unsigned char* ws = (unsigned char*)d_ws;
    u16* connB = (u16*)(ws + OFF_CONNB);
    u16* yT    = (u16*)(ws + OFF_YT);
    u16* xA    = (u16*)(ws + OFF_XA);
    u16* xB    = (u16*)(ws + OFF_XB);
    u16* wA    = (u16*)(ws + OFF_WA);
    float* bW  = (float*)(ws + OFF_BW);

    // conn: 16*512*512*12 = 50,331,648 elems -> n8 = 6,291,456  (R2 bug: was 2x)
    k_cast_bf16<<<dim3(2048), dim3(256), 0, stream>>>(conn, connB, 6291456u);
    // node: 524,288 elems -> n8 = 65,536
    k_cast_bf16<<<dim3(256), dim3(256), 0, stream>>>(node, xA, 65536u);
    k_w_pack<<<dim3(576), dim3(256), 0, stream>>>(filters, wA);
    k_bondw<<<dim3(8192), dim3(192), 0, stream>>>(bond, filters, bW);

    u16* xc = xA; u16* xn = xB;
    for (int j = 0; j < 6; ++j) {
      int i = j >> 1;
      k_stageA<<<dim3(16, 16), dim3(256), 0, stream>>>(xc, wA + (size_t)i * 49152, yT);
      k_stageB<<<dim3(128), dim3(512), 0, stream>>>(connB, yT, bW + (size_t)i * 524288,
                                                    node, outF, xn, j & 1, j == 5);
      u16* tmp = xc; xc = xn; xn = tmp;
    }
  } else {
    float* buf = (float*)d_ws;
    const float* xc = node;
    for (int j = 0; j < 6; ++j) {
      int i = j >> 1;
      float* dst = (j & 1) ? outF : buf;
      k_fb_conv<<<dim3(512, 16), dim3(256), 0, stream>>>(xc, conn, bond,
                                                         filters + (size_t)i * 50688,
                                                         node, dst, j & 1);
      xc = dst;
    }
  }
}

// Round 4
// 316.513 us; speedup vs baseline: 1.6880x; 1.6880x over previous
//
#include <hip/hip_runtime.h>

// ChemResBlock: S=16, A=512, F=64, L=12, 3 layers x 2 convs (shared weights/layer).
// Re-associated: yT[s][o][k*12+l] = sum_f x[s,k,f] w[o,l,f]   (stage A, tiny)
//   out[s,a,o] = sum_{kl} connB[s,a,kl] * yT[s][o][kl] + bondW (+node), relu
// Stage B: BK=128, K-split 4 -> f32 partials; k_finalize reduces + epilogue.

typedef __attribute__((ext_vector_type(8))) short bf16x8;
typedef __attribute__((ext_vector_type(4))) float f32x4;
typedef unsigned short u16;
typedef unsigned int u32;

__device__ __forceinline__ u16 f2bf(float f) {
  union { float f; u32 u; } x; x.f = f;
  u32 r = x.u + 0x7fffu + ((x.u >> 16) & 1u);   // RNE
  return (u16)(r >> 16);
}

__device__ __forceinline__ void gload16(const void* g, void* l) {
  __builtin_amdgcn_global_load_lds((const __attribute__((address_space(1))) u32*)g,
                                   (__attribute__((address_space(3))) u32*)l, 16, 0, 0);
}

// ---------- prep ----------

__global__ __launch_bounds__(256) void k_cast_bf16(const float* __restrict__ src,
                                                   u16* __restrict__ dst, unsigned n8) {
  const unsigned stride = gridDim.x * 256;
  for (unsigned j = blockIdx.x * 256 + threadIdx.x; j < n8; j += stride) {
    const float4* s4 = (const float4*)src;
    float4 a = s4[2 * (size_t)j], b = s4[2 * (size_t)j + 1];
    ushort4 lo, hi;
    lo.x = f2bf(a.x); lo.y = f2bf(a.y); lo.z = f2bf(a.z); lo.w = f2bf(a.w);
    hi.x = f2bf(b.x); hi.y = f2bf(b.y); hi.z = f2bf(b.z); hi.w = f2bf(b.w);
    ((ushort4*)dst)[2 * (size_t)j] = lo;
    ((ushort4*)dst)[2 * (size_t)j + 1] = hi;
  }
}

// filters (3,64,12,66) -> wA [i][(l*64+o)][f] bf16 (drop bond cols)
__global__ __launch_bounds__(256) void k_w_pack(const float* __restrict__ filters,
                                                u16* __restrict__ wA) {
  int tid = blockIdx.x * 256 + threadIdx.x;  // < 3*768*64 = 147456
  int i = tid / 49152;
  int rem = tid - i * 49152;
  int row = rem >> 6, f = rem & 63;          // row = l*64+o
  int l = row >> 6, o = row & 63;
  wA[tid] = f2bf(filters[((size_t)((i * 64 + o) * 12 + l)) * 66 + f]);
}

// bondW[i][(s*512+a)*64+o] = sum_{l,j} bond[s,a,l,j] * filters[i,o,l,64+j]
__global__ __launch_bounds__(192) void k_bondw(const float* __restrict__ bond,
                                               const float* __restrict__ filters,
                                               float* __restrict__ bondW) {
  int blk = blockIdx.x;                      // s*512 + a
  int t = threadIdx.x;                       // 192 = 3 filters x 64 o
  __shared__ float lb[24];
  if (t < 24) lb[t] = bond[(size_t)blk * 24 + t];
  __syncthreads();
  int i = t >> 6, o = t & 63;
  float acc = 0.f;
#pragma unroll
  for (int l = 0; l < 12; ++l) {
    const float* wr = filters + ((size_t)((i * 64 + o) * 12 + l)) * 66 + 64;
    acc += lb[l * 2 + 0] * wr[0] + lb[l * 2 + 1] * wr[1];
  }
  bondW[(size_t)i * 524288 + (size_t)blk * 64 + o] = acc;
}

// ---------- stage A: yT[s][o][k*12+l] = sum_f x[s,k,f] wA[(l*64+o)][f] ----------
__global__ __launch_bounds__(256) void k_stageA(const u16* __restrict__ x,
                                                const u16* __restrict__ wA,
                                                u16* __restrict__ yT) {
  const int s = blockIdx.y, k0 = blockIdx.x * 32;
  __shared__ u16 Z[12 * 64 * 36];            // 55 KiB
  const int tid = threadIdx.x, lane = tid & 63, wid = tid >> 6;
  const int r = lane & 15, g = lane >> 4;
  const u16* xb = x + (size_t)s * 32768 + (size_t)k0 * 64;

  bf16x8 bv[2][2];                           // [kt][ks]: x frags, col=k, K=f
#pragma unroll
  for (int kt = 0; kt < 2; ++kt)
#pragma unroll
    for (int ks = 0; ks < 2; ++ks)
      bv[kt][ks] = *(const bf16x8*)&xb[(size_t)(kt * 16 + r) * 64 + ks * 32 + g * 8];

#pragma unroll
  for (int lw = 0; lw < 3; ++lw) {
    const int l = wid * 3 + lw;
    f32x4 acc[4][2] = {};                    // [ot][kt]
#pragma unroll
    for (int ks = 0; ks < 2; ++ks)
#pragma unroll
      for (int ot = 0; ot < 4; ++ot) {
        bf16x8 av = *(const bf16x8*)&wA[(size_t)(l * 64 + ot * 16 + r) * 64 + ks * 32 + g * 8];
#pragma unroll
        for (int kt = 0; kt < 2; ++kt)
          acc[ot][kt] = __builtin_amdgcn_mfma_f32_16x16x32_bf16(av, bv[kt][ks], acc[ot][kt], 0, 0, 0);
      }
#pragma unroll
    for (int ot = 0; ot < 4; ++ot)
#pragma unroll
      for (int kt = 0; kt < 2; ++kt)
#pragma unroll
        for (int r2 = 0; r2 < 4; ++r2) {
          int o = ot * 16 + g * 4 + r2, k = kt * 16 + r;
          Z[l * 2304 + o * 36 + k] = f2bf(acc[ot][kt][r2]);
        }
  }
  __syncthreads();
  u16* yb = yT + (size_t)s * 393216;
#pragma unroll
  for (int it = 0; it < 8; ++it) {
    int idx = it * 256 + tid;                // 64 o x 32 k
    int o = idx >> 5, k = idx & 31;
    u16 v[12];
#pragma unroll
    for (int l = 0; l < 12; ++l) v[l] = Z[l * 2304 + o * 36 + k];
    ushort4* dst = (ushort4*)&yb[(size_t)o * 6144 + (size_t)(k0 + k) * 12];
    ushort4 w0, w1, w2;
    w0.x = v[0]; w0.y = v[1]; w0.z = v[2]; w0.w = v[3];
    w1.x = v[4]; w1.y = v[5]; w1.z = v[6]; w1.w = v[7];
    w2.x = v[8]; w2.y = v[9]; w2.z = v[10]; w2.w = v[11];
    dst[0] = w0; dst[1] = w1; dst[2] = w2;
  }
}

// ---------- stage B: partial[kq][s,a,o] = connB[s,a,k0:k0+1536] . yT[s,o,k0:k0+1536]
// Mtile=64 x N=64, BK=128, 12 iters, 8 waves. LDS rows 256B, 16B-slot XOR (row&7).
__global__ __launch_bounds__(512) void k_stageB(const u16* __restrict__ connB,
                                                const u16* __restrict__ yT,
                                                float* __restrict__ pOut) {
  const int b = blockIdx.x;                  // 512 blocks
  const int xcd = b & 7, rest = b >> 3;
  const int s = xcd * 2 + (rest & 1);
  const int rest2 = rest >> 1;
  const int bx = rest2 & 7, kq = rest2 >> 3; // bx: m-tile, kq: k-quarter
  const int row0 = bx * 64;
  const int k0 = kq * 1536;
  const u16* Ab = connB + (size_t)s * 3145728 + (size_t)row0 * 6144 + k0;
  const u16* Bb = yT + (size_t)s * 393216 + k0;
  __shared__ __align__(16) u16 lA[2][64 * 128];
  __shared__ __align__(16) u16 lB[2][64 * 128];
  const int tid = threadIdx.x, lane = tid & 63, wid = tid >> 6;
  const int r = lane & 15, g = lane >> 4;
  const int wr = wid & 3, wc = wid >> 2;     // wave M-quarter / N-half

  const int isA = wid < 4;
  const int wseg = (isA ? wid : wid - 4) * 16;   // this wave's 16-row staging segment
  const u16* sbase = isA ? Ab : Bb;
  u16* const lbase[2] = { isA ? lA[0] : lB[0], isA ? lA[1] : lB[1] };
  // per-lane staging source (row, swizzled slot); dest is wave-uniform rowgroup base
  const int srow_off = lane >> 4;            // row within 4-row group
  const int sslot = lane & 15;

  f32x4 acc[2] = {};

#define STAGE(ST, BUF)                                                          \
  {                                                                             \
    u16* lds = lbase[BUF];                                                      \
    _Pragma("unroll")                                                           \
    for (int rg = 0; rg < 4; ++rg) {                                            \
      const int row = wseg + rg * 4 + srow_off;                                 \
      const int slot = sslot ^ (row & 7);                                       \
      gload16(sbase + (size_t)row * 6144 + (ST) * 128 + slot * 8,               \
              lds + (wseg + rg * 4) * 128);                                     \
    }                                                                           \
  }

  STAGE(0, 0);
  __syncthreads();
  for (int st = 0; st < 12; ++st) {
    const int cur = st & 1;
    if (st < 11) STAGE(st + 1, cur ^ 1);
    bf16x8 av[4], bv[4][2];
    const int arow = wr * 16 + r;
#pragma unroll
    for (int ks = 0; ks < 4; ++ks) {
      av[ks] = *(const bf16x8*)&lA[cur][arow * 128 + ((((ks << 2) + g) ^ (arow & 7)) << 3)];
#pragma unroll
      for (int c = 0; c < 2; ++c) {
        const int col = wc * 32 + c * 16 + r;
        bv[ks][c] = *(const bf16x8*)&lB[cur][col * 128 + ((((ks << 2) + g) ^ (col & 7)) << 3)];
      }
    }
#pragma unroll
    for (int ks = 0; ks < 4; ++ks)
#pragma unroll
      for (int c = 0; c < 2; ++c)
        acc[c] = __builtin_amdgcn_mfma_f32_16x16x32_bf16(av[ks], bv[ks][c], acc[c], 0, 0, 0);
    __syncthreads();
  }
#undef STAGE
  // partial write: f32, [kq][s*512+row][o]
  float* po = pOut + (size_t)kq * 524288 + ((size_t)s * 512 + row0) * 64;
#pragma unroll
  for (int c = 0; c < 2; ++c)
#pragma unroll
    for (int r2 = 0; r2 < 4; ++r2) {
      int m = wr * 16 + g * 4 + r2;
      int o = wc * 32 + c * 16 + r;
      po[m * 64 + o] = acc[c][r2];
    }
}

// ---------- finalize: out = relu(sum_q p[q] + bW (+node)); write bf16 xn (+f32 outF) ----
__global__ __launch_bounds__(256) void k_finalize(const float* __restrict__ pOut,
                                                  const float* __restrict__ bW,
                                                  const float* __restrict__ node,
                                                  float* __restrict__ outF,
                                                  u16* __restrict__ xn,
                                                  int addNode, int writeF32) {
  size_t e = ((size_t)blockIdx.x * 256 + threadIdx.x) * 4;   // < 524288
  float4 v0 = *(const float4*)&pOut[e];
  float4 v1 = *(const float4*)&pOut[524288 + e];
  float4 v2 = *(const float4*)&pOut[1048576 + e];
  float4 v3 = *(const float4*)&pOut[1572864 + e];
  float4 bw = *(const float4*)&bW[e];
  float4 rv;
  rv.x = v0.x + v1.x + v2.x + v3.x + bw.x;
  rv.y = v0.y + v1.y + v2.y + v3.y + bw.y;
  rv.z = v0.z + v1.z + v2.z + v3.z + bw.z;
  rv.w = v0.w + v1.w + v2.w + v3.w + bw.w;
  if (addNode) {
    float4 nd = *(const float4*)&node[e];
    rv.x += nd.x; rv.y += nd.y; rv.z += nd.z; rv.w += nd.w;
  }
  rv.x = fmaxf(rv.x, 0.f); rv.y = fmaxf(rv.y, 0.f);
  rv.z = fmaxf(rv.z, 0.f); rv.w = fmaxf(rv.w, 0.f);
  if (writeF32) *(float4*)&outF[e] = rv;
  ushort4 h;
  h.x = f2bf(rv.x); h.y = f2bf(rv.y); h.z = f2bf(rv.z); h.w = f2bf(rv.w);
  *(ushort4*)&xn[e] = h;
}

// ---------- fallback (f32, correct, slow) if ws too small ----------
__global__ __launch_bounds__(256) void k_fb_conv(const float* __restrict__ x,
                                                 const float* __restrict__ conn,
                                                 const float* __restrict__ bond,
                                                 const float* __restrict__ filt,
                                                 const float* __restrict__ node,
                                                 float* __restrict__ out, int addNode) {
  const int s = blockIdx.y, a = blockIdx.x;
  const int t = threadIdx.x;
  const int f = t & 63, lg = t >> 6;
  __shared__ float ncv[12 * 64];
  __shared__ float red[4][64];
  const float* cb = conn + ((size_t)(s * 512 + a)) * 6144;
  const float* xb = x + (size_t)s * 32768;
  float a0 = 0.f, a1 = 0.f, a2 = 0.f;
  for (int k = 0; k < 512; ++k) {
    float xv = xb[k * 64 + f];
    const float* cr = cb + k * 12 + lg * 3;
    a0 += cr[0] * xv; a1 += cr[1] * xv; a2 += cr[2] * xv;
  }
  ncv[(lg * 3 + 0) * 64 + f] = a0;
  ncv[(lg * 3 + 1) * 64 + f] = a1;
  ncv[(lg * 3 + 2) * 64 + f] = a2;
  __syncthreads();
  float p = 0.f;
  for (int l = lg * 3; l < lg * 3 + 3; ++l) {
    const float* wr = filt + ((size_t)(f * 12 + l)) * 66;
    float q = 0.f;
    for (int f2 = 0; f2 < 64; ++f2) q += ncv[l * 64 + f2] * wr[f2];
    q += bond[((size_t)(s * 512 + a) * 12 + l) * 2 + 0] * wr[64];
    q += bond[((size_t)(s * 512 + a) * 12 + l) * 2 + 1] * wr[65];
    p += q;
  }
  red[lg][f] = p;
  __syncthreads();
  if (t < 64) {
    float v = red[0][t] + red[1][t] + red[2][t] + red[3][t];
    if (addNode) v += node[((size_t)(s * 512 + a)) * 64 + t];
    out[((size_t)(s * 512 + a)) * 64 + t] = fmaxf(v, 0.f);
  }
}

extern "C" void kernel_launch(void* const* d_in, const int* in_sizes, int n_in,
                              void* d_out, int out_size, void* d_ws, size_t ws_size,
                              hipStream_t stream) {
  (void)in_sizes; (void)n_in; (void)out_size;
  const float* node    = (const float*)d_in[0];
  const float* conn    = (const float*)d_in[1];
  const float* bond    = (const float*)d_in[2];
  const float* filters = (const float*)d_in[3];
  float* outF = (float*)d_out;

  const size_t OFF_CONNB = 0;           // 16*512*6144*2  = 100,663,296
  const size_t OFF_YT    = 100663296;   // 16*64*6144*2   =  12,582,912
  const size_t OFF_XA    = 113246208;   // 16*512*64*2    =   1,048,576
  const size_t OFF_XB    = 114294784;   //                    1,048,576
  const size_t OFF_WA    = 115343360;   // 3*768*64*2     =     294,912
  const size_t OFF_BW    = 115638272;   // 3*16*512*64*4  =   6,291,456
  const size_t OFF_POUT  = 121929728;   // 4*16*512*64*4  =   8,388,608
  const size_t WS_NEED   = 130318336;

  if (ws_size >= WS_NEED) {
    unsigned char* ws = (unsigned char*)d_ws;
    u16* connB = (u16*)(ws + OFF_CONNB);
    u16* yT    = (u16*)(ws + OFF_YT);
    u16* xA    = (u16*)(ws + OFF_XA);
    u16* xB    = (u16*)(ws + OFF_XB);
    u16* wA    = (u16*)(ws + OFF_WA);
    float* bW  = (float*)(ws + OFF_BW);
    float* pO  = (float*)(ws + OFF_POUT);

    // conn: 50,331,648 elems -> n8 = 6,291,456
    k_cast_bf16<<<dim3(2048), dim3(256), 0, stream>>>(conn, connB, 6291456u);
    // node: 524,288 elems -> n8 = 65,536
    k_cast_bf16<<<dim3(256), dim3(256), 0, stream>>>(node, xA, 65536u);
    k_w_pack<<<dim3(576), dim3(256), 0, stream>>>(filters, wA);
    k_bondw<<<dim3(8192), dim3(192), 0, stream>>>(bond, filters, bW);

    u16* xc = xA; u16* xn = xB;
    for (int j = 0; j < 6; ++j) {
      int i = j >> 1;
      k_stageA<<<dim3(16, 16), dim3(256), 0, stream>>>(xc, wA + (size_t)i * 49152, yT);
      k_stageB<<<dim3(512), dim3(512), 0, stream>>>(connB, yT, pO);
      k_finalize<<<dim3(512), dim3(256), 0, stream>>>(pO, bW + (size_t)i * 524288,
                                                      node, outF, xn, j & 1, j == 5);
      u16* tmp = xc; xc = xn; xn = tmp;
    }
  } else {
    float* buf = (float*)d_ws;
    const float* xc = node;
    for (int j = 0; j < 6; ++j) {
      int i = j >> 1;
      float* dst = (j & 1) ? outF : buf;
      k_fb_conv<<<dim3(512, 16), dim3(256), 0, stream>>>(xc, conn, bond,
                                                         filters + (size_t)i * 50688,
                                                         node, dst, j & 1);
      xc = dst;
    }
  }
}